// Round 4
// baseline (425.472 us; speedup 1.0000x reference)
//
#include <hip/hip_runtime.h>

// ---------------- constants ----------------
#define D_MODEL 768
#define D_INNER 1536
#define NXZ     3072   // 2*D_INNER
#define BATCH   2
#define SEQ     8192
#define MTOT    (BATCH*SEQ)   // 16384
#define XZLD    16448  // xzT leading dim: MTOT + 64 elems (+128B) breaks 32KB pow-2 stride
#define CHUNK   128
#define WARM    64            // 0.9^64 ~ 1.2e-3; output-level error ~1e-6 << 3.5e-4 threshold

typedef _Float16 v8h __attribute__((ext_vector_type(8)));
typedef _Float16 v4h __attribute__((ext_vector_type(4)));
typedef float    v4f __attribute__((ext_vector_type(4)));
typedef _Float16 f16;

// ---------------- prep: f32 -> f16 convert ----------------
__global__ void k_cvt(const float* __restrict__ in, f16* __restrict__ out, int n4) {
  int i = blockIdx.x * blockDim.x + threadIdx.x;
  if (i < n4) {
    float4 v = reinterpret_cast<const float4*>(in)[i];
    v4h o;
    o[0] = (f16)v.x; o[1] = (f16)v.y; o[2] = (f16)v.z; o[3] = (f16)v.w;
    reinterpret_cast<v4h*>(out)[i] = o;
  }
}

// ---------------- prep: transpose (R,C) f32 -> (C,R) f16 ----------------
__global__ void k_transpose_cvt(const float* __restrict__ in, f16* __restrict__ out,
                                int R, int C) {
  __shared__ float tile[32][33];
  int c0 = blockIdx.x * 32, r0 = blockIdx.y * 32;
  int tx = threadIdx.x, ty = threadIdx.y;   // 32 x 8
#pragma unroll
  for (int i = 0; i < 32; i += 8)
    tile[ty + i][tx] = in[(long)(r0 + ty + i) * C + (c0 + tx)];
  __syncthreads();
#pragma unroll
  for (int i = 0; i < 32; i += 8)
    out[(long)(c0 + ty + i) * R + (r0 + tx)] = (f16)tile[tx][ty + i];
}

// async global->LDS, 16B per lane, dest = wave-uniform base + lane*16
__device__ __forceinline__ void gload_lds16(const void* g, void* l) {
  __builtin_amdgcn_global_load_lds((const __attribute__((address_space(1))) void*)g,
                                   (__attribute__((address_space(3))) void*)l, 16, 0, 0);
}

// ---------------- MFMA GEMM: C = A[M,K] * Bt[N,K]^T + bias ----------------
// m97 structure + XOR bank swizzle (R3: verified conflicts -> 0).
// OUT_MODE 0: f32 C[m][n].  OUT_MODE 1: f16 transposed C_T[n][m] with leading
// dim XZLD (padded, breaks pow-2 stride camping), packed 8B stores.
template <int OUT_MODE>
__launch_bounds__(256, 2)
__global__ void k_gemm_bt(const f16* __restrict__ A, const f16* __restrict__ Bt,
                          const float* __restrict__ bias, void* __restrict__ Cv,
                          int M, int N, int K) {
  __shared__ f16 As[128][32];   // unpadded: global_load_lds placement is base + lane*16
  __shared__ f16 Bs[128][32];
  const int tid  = threadIdx.x;
  const int lane = tid & 63;
  const int wave = tid >> 6;
  const int wm   = (wave >> 1) * 64;
  const int wn   = (wave & 1) * 64;
  const int m16  = lane & 15;
  const int quad = lane >> 4;
  const int rsw  = (m16 >> 1) & 3;           // read-side swizzle
  const long m0 = (long)blockIdx.y * 128;
  const long n0 = (long)blockIdx.x * 128;

  v4f acc[4][4];
#pragma unroll
  for (int i = 0; i < 4; i++)
#pragma unroll
    for (int j = 0; j < 4; j++)
#pragma unroll
      for (int r = 0; r < 4; r++) acc[i][j][r] = 0.f;

  // staging: lane l -> row wave*16 + l/4, swizzled global chunk
  const int srow = wave * 16 + (lane >> 2);
  const int scol = (((lane & 3) ^ ((lane >> 3) & 3)) << 3);
  const f16* Ag = A  + (m0 + srow) * (long)K + scol;
  const f16* Bg = Bt + (n0 + srow) * (long)K + scol;
  f16* AsW0 = &As[wave * 16][0];
  f16* AsW1 = &As[64 + wave * 16][0];
  f16* BsW0 = &Bs[wave * 16][0];
  f16* BsW1 = &Bs[64 + wave * 16][0];

  for (int k0 = 0; k0 < K; k0 += 32) {
    gload_lds16(Ag,                 AsW0);
    gload_lds16(Ag + (long)64 * K,  AsW1);
    gload_lds16(Bg,                 BsW0);
    gload_lds16(Bg + (long)64 * K,  BsW1);
    Ag += 32; Bg += 32;
    __syncthreads();
    v8h af[4], bfr[4];
#pragma unroll
    for (int i = 0; i < 4; i++) af[i]  = *(const v8h*)&As[wm + i * 16 + m16][(quad ^ rsw) * 8];
#pragma unroll
    for (int j = 0; j < 4; j++) bfr[j] = *(const v8h*)&Bs[wn + j * 16 + m16][(quad ^ rsw) * 8];
#pragma unroll
    for (int i = 0; i < 4; i++)
#pragma unroll
      for (int j = 0; j < 4; j++)
        acc[i][j] = __builtin_amdgcn_mfma_f32_16x16x32_f16(af[i], bfr[j], acc[i][j], 0, 0, 0);
    __syncthreads();
  }

  if (OUT_MODE == 1) {
    // transposed f16 out: C_T[n][m] with padded leading dim XZLD
    f16* Ct = (f16*)Cv;
#pragma unroll
    for (int i = 0; i < 4; i++) {
#pragma unroll
      for (int j = 0; j < 4; j++) {
        const long n = n0 + wn + j * 16 + m16;
        const float bv = bias[n];
        v4h pk;
#pragma unroll
        for (int r = 0; r < 4; r++) pk[r] = (f16)(acc[i][j][r] + bv);
        *(v4h*)&Ct[n * (long)XZLD + (m0 + wm + i * 16 + quad * 4)] = pk;
      }
    }
  } else {
    float* C = (float*)Cv;
#pragma unroll
    for (int i = 0; i < 4; i++) {
#pragma unroll
      for (int j = 0; j < 4; j++) {
        const long n = n0 + wn + j * 16 + m16;
        const float bv = bias[n];
#pragma unroll
        for (int r = 0; r < 4; r++) {
          const long m = m0 + wm + i * 16 + quad * 4 + r;
          C[m * N + n] = acc[i][j][r] + bv;
        }
      }
    }
  }
}

// ---------------- conv4 + SiLU + EMA scan + gate ----------------
// xzT stored [n][XZLD] (padded): each thread owns channel c and reads its
// time series contiguously via 16B v8h loads; padded stride spreads rows
// across L2 sets / DRAM channels. y written [m][c] (GEMM2 layout).
__global__ void k_conv_scan(const f16* __restrict__ xzT, const float* __restrict__ conv_w,
                            const float* __restrict__ conv_b, const float* __restrict__ Dp_,
                            f16* __restrict__ y) {
  const int c  = blockIdx.y * 256 + threadIdx.x;   // 0..1535
  const int b  = blockIdx.z;
  const int t0 = blockIdx.x * CHUNK;
  const float w0 = conv_w[c * 4 + 0], w1 = conv_w[c * 4 + 1];
  const float w2 = conv_w[c * 4 + 2], w3 = conv_w[c * 4 + 3];
  const float cb = conv_b[c], Dp = Dp_[c];
  const f16* xr = xzT + (long)c * XZLD + (long)b * SEQ;
  const f16* zr = xzT + (long)(c + D_INNER) * XZLD + (long)b * SEQ;
  f16* yout = y + (long)b * SEQ * D_INNER + c;

  const int ts = (t0 >= WARM) ? (t0 - WARM) : 0;
  float xm3 = 0.f, xm2 = 0.f, xm1 = 0.f;
  if (ts >= 3) { xm3 = (float)xr[ts - 3]; xm2 = (float)xr[ts - 2]; xm1 = (float)xr[ts - 1]; }
  float h = 0.f;

  // warm-up (no output): 8 v8h loads
  for (int t8 = ts; t8 < t0; t8 += 8) {
    v8h xv = *(const v8h*)&xr[t8];
#pragma unroll
    for (int k = 0; k < 8; k++) {
      float xt = (float)xv[k];
      float u = w0 * xm3 + w1 * xm2 + w2 * xm1 + w3 * xt + cb;
      float v = u / (1.f + __expf(-u));
      h = 0.9f * h + 0.1f * v;
      xm3 = xm2; xm2 = xm1; xm1 = xt;
    }
  }
  // main chunk
  for (int t8 = t0; t8 < t0 + CHUNK; t8 += 8) {
    v8h xv = *(const v8h*)&xr[t8];
    v8h zv8 = *(const v8h*)&zr[t8];
#pragma unroll
    for (int k = 0; k < 8; k++) {
      float xt = (float)xv[k];
      float u = w0 * xm3 + w1 * xm2 + w2 * xm1 + w3 * xt + cb;
      float v = u / (1.f + __expf(-u));
      h = 0.9f * h + 0.1f * v;
      float zv = (float)zv8[k];
      float g = zv / (1.f + __expf(-zv));
      yout[(long)(t8 + k) * D_INNER] = (f16)((v * Dp + h) * g);
      xm3 = xm2; xm2 = xm1; xm1 = xt;
    }
  }
}

// ---------------- launch ----------------
extern "C" void kernel_launch(void* const* d_in, const int* in_sizes, int n_in,
                              void* d_out, int out_size, void* d_ws, size_t ws_size,
                              hipStream_t stream) {
  const float* x       = (const float*)d_in[0];
  const float* in_w    = (const float*)d_in[1];
  const float* in_b    = (const float*)d_in[2];
  const float* conv_w  = (const float*)d_in[3];
  const float* conv_b  = (const float*)d_in[4];
  // d_in[5..8] (xp_w, xp_b, dt_w, dt_b) are dead code in the reference
  const float* D_param = (const float*)d_in[9];
  const float* out_w   = (const float*)d_in[10];
  const float* out_b   = (const float*)d_in[11];
  float* out = (float*)d_out;

  char* p = (char*)d_ws;
  f16* xb    = (f16*)p; p += (size_t)MTOT * D_MODEL * 2;   // 25.2 MB
  f16* wInT  = (f16*)p; p += (size_t)NXZ * D_MODEL * 2;    //  4.7 MB
  f16* wOutT = (f16*)p; p += (size_t)D_MODEL * D_INNER * 2;//  2.4 MB
  f16* xzT   = (f16*)p; p += (size_t)NXZ * XZLD * 2;       // 101.1 MB (transposed, padded LD)
  f16* yb    = (f16*)p; p += (size_t)MTOT * D_INNER * 2;   // 50.3 MB

  // prep
  k_cvt<<<(MTOT * D_MODEL / 4 + 255) / 256, 256, 0, stream>>>(x, xb, MTOT * D_MODEL / 4);
  k_transpose_cvt<<<dim3(NXZ / 32, D_MODEL / 32), dim3(32, 8), 0, stream>>>(in_w, wInT, D_MODEL, NXZ);
  k_transpose_cvt<<<dim3(D_MODEL / 32, D_INNER / 32), dim3(32, 8), 0, stream>>>(out_w, wOutT, D_INNER, D_MODEL);

  // xz^T = (x @ in_w + in_b)^T   (f16, [n][XZLD])
  k_gemm_bt<1><<<dim3(NXZ / 128, MTOT / 128), 256, 0, stream>>>(xb, wInT, in_b, xzT, MTOT, NXZ, D_MODEL);

  // conv + silu + EMA scan + gate -> y (f16, [m][c])
  k_conv_scan<<<dim3(SEQ / CHUNK, D_INNER / 256, BATCH), 256, 0, stream>>>(xzT, conv_w, conv_b, D_param, yb);

  // out = y @ out_w + out_b  (f32, [m][n])
  k_gemm_bt<0><<<dim3(D_MODEL / 128, MTOT / 128), 256, 0, stream>>>(yb, wOutT, out_b, out, MTOT, D_MODEL, D_INNER);
}

// Round 5
// 348.315 us; speedup vs baseline: 1.2215x; 1.2215x over previous
//
#include <hip/hip_runtime.h>

// ---------------- constants ----------------
#define D_MODEL 768
#define D_INNER 1536
#define NXZ     3072   // 2*D_INNER
#define BATCH   2
#define SEQ     8192
#define MTOT    (BATCH*SEQ)   // 16384
#define WARM    64            // 0.9^64 ~ 1.2e-3; output-level error ~1e-6 << 3.5e-4 threshold

typedef _Float16 v8h __attribute__((ext_vector_type(8)));
typedef _Float16 v4h __attribute__((ext_vector_type(4)));
typedef float    v4f __attribute__((ext_vector_type(4)));
typedef _Float16 f16;

// ---------------- prep: f32 -> f16 convert ----------------
__global__ void k_cvt(const float* __restrict__ in, f16* __restrict__ out, int n4) {
  int i = blockIdx.x * blockDim.x + threadIdx.x;
  if (i < n4) {
    float4 v = reinterpret_cast<const float4*>(in)[i];
    v4h o;
    o[0] = (f16)v.x; o[1] = (f16)v.y; o[2] = (f16)v.z; o[3] = (f16)v.w;
    reinterpret_cast<v4h*>(out)[i] = o;
  }
}

// ---------------- prep: transpose (R,C) f32 -> (C,R) f16 ----------------
__global__ void k_transpose_cvt(const float* __restrict__ in, f16* __restrict__ out,
                                int R, int C) {
  __shared__ float tile[32][33];
  int c0 = blockIdx.x * 32, r0 = blockIdx.y * 32;
  int tx = threadIdx.x, ty = threadIdx.y;   // 32 x 8
#pragma unroll
  for (int i = 0; i < 32; i += 8)
    tile[ty + i][tx] = in[(long)(r0 + ty + i) * C + (c0 + tx)];
  __syncthreads();
#pragma unroll
  for (int i = 0; i < 32; i += 8)
    out[(long)(c0 + ty + i) * R + (r0 + tx)] = (f16)tile[tx][ty + i];
}

// async global->LDS, 16B per lane, dest = wave-uniform base + lane*16
__device__ __forceinline__ void gload_lds16(const void* g, void* l) {
  __builtin_amdgcn_global_load_lds((const __attribute__((address_space(1))) void*)g,
                                   (__attribute__((address_space(3))) void*)l, 16, 0, 0);
}

// ---------------- MFMA GEMM: C = A[M,K] * Bt[N,K]^T + bias ----------------
// R2 config (best measured): m97 staging + XOR bank swizzle (conflicts=0),
// plain row-major C epilogue. F16OUT: f16 C[m][n]; else f32 C[m][n].
template <bool F16OUT>
__launch_bounds__(256, 2)
__global__ void k_gemm_bt(const f16* __restrict__ A, const f16* __restrict__ Bt,
                          const float* __restrict__ bias, void* __restrict__ Cv,
                          int M, int N, int K) {
  __shared__ f16 As[128][32];   // unpadded: global_load_lds placement is base + lane*16
  __shared__ f16 Bs[128][32];
  const int tid  = threadIdx.x;
  const int lane = tid & 63;
  const int wave = tid >> 6;
  const int wm   = (wave >> 1) * 64;
  const int wn   = (wave & 1) * 64;
  const int m16  = lane & 15;
  const int quad = lane >> 4;
  const int rsw  = (m16 >> 1) & 3;           // read-side swizzle
  const long m0 = (long)blockIdx.y * 128;
  const long n0 = (long)blockIdx.x * 128;

  v4f acc[4][4];
#pragma unroll
  for (int i = 0; i < 4; i++)
#pragma unroll
    for (int j = 0; j < 4; j++)
#pragma unroll
      for (int r = 0; r < 4; r++) acc[i][j][r] = 0.f;

  // staging: lane l -> row wave*16 + l/4, swizzled global chunk
  const int srow = wave * 16 + (lane >> 2);
  const int scol = (((lane & 3) ^ ((lane >> 3) & 3)) << 3);
  const f16* Ag = A  + (m0 + srow) * (long)K + scol;
  const f16* Bg = Bt + (n0 + srow) * (long)K + scol;
  f16* AsW0 = &As[wave * 16][0];
  f16* AsW1 = &As[64 + wave * 16][0];
  f16* BsW0 = &Bs[wave * 16][0];
  f16* BsW1 = &Bs[64 + wave * 16][0];

  for (int k0 = 0; k0 < K; k0 += 32) {
    gload_lds16(Ag,                 AsW0);
    gload_lds16(Ag + (long)64 * K,  AsW1);
    gload_lds16(Bg,                 BsW0);
    gload_lds16(Bg + (long)64 * K,  BsW1);
    Ag += 32; Bg += 32;
    __syncthreads();
    v8h af[4], bfr[4];
#pragma unroll
    for (int i = 0; i < 4; i++) af[i]  = *(const v8h*)&As[wm + i * 16 + m16][(quad ^ rsw) * 8];
#pragma unroll
    for (int j = 0; j < 4; j++) bfr[j] = *(const v8h*)&Bs[wn + j * 16 + m16][(quad ^ rsw) * 8];
#pragma unroll
    for (int i = 0; i < 4; i++)
#pragma unroll
      for (int j = 0; j < 4; j++)
        acc[i][j] = __builtin_amdgcn_mfma_f32_16x16x32_f16(af[i], bfr[j], acc[i][j], 0, 0, 0);
    __syncthreads();
  }

#pragma unroll
  for (int i = 0; i < 4; i++) {
#pragma unroll
    for (int j = 0; j < 4; j++) {
      const long n = n0 + wn + j * 16 + m16;
      const float bv = bias[n];
#pragma unroll
      for (int r = 0; r < 4; r++) {
        const long m = m0 + wm + i * 16 + quad * 4 + r;
        float v = acc[i][j][r] + bv;
        if (F16OUT) ((f16*)Cv)[m * N + n] = (f16)v;
        else        ((float*)Cv)[m * N + n] = v;
      }
    }
  }
}

// ---------------- conv4 + SiLU + EMA scan + gate (LDS-staged) ----------------
// Block = 256 channels x 128 output timesteps (+64 warm). Three 64-t panels:
// stage x (and z for main panels) into LDS via coalesced v8h loads (16B/lane,
// high MLP), then each thread scans its channel from LDS (2B reads, 2 lanes/
// bank = free). y written [m][c] coalesced (wave = 128B rows).
__global__ void k_conv_scan(const f16* __restrict__ xz, const float* __restrict__ conv_w,
                            const float* __restrict__ conv_b, const float* __restrict__ Dp_,
                            f16* __restrict__ y) {
  __shared__ f16 xs[64][256];   // 32 KB
  __shared__ f16 zs[64][256];   // 32 KB
  const int tid = threadIdx.x;
  const int c0  = blockIdx.y * 256;
  const int c   = c0 + tid;
  const int b   = blockIdx.z;
  const int t0  = blockIdx.x * 128;
  const float w0 = conv_w[c * 4 + 0], w1 = conv_w[c * 4 + 1];
  const float w2 = conv_w[c * 4 + 2], w3 = conv_w[c * 4 + 3];
  const float cb = conv_b[c], Dp = Dp_[c];
  const long mb = (long)b * SEQ;

  float xm3 = 0.f, xm2 = 0.f, xm1 = 0.f, h = 0.f;
  const int ts = t0 - WARM;   // panel-0 start; < 0 only for blockIdx.x==0
  if (t0 > 0) {
    xm3 = (float)xz[(mb + ts - 3) * (long)NXZ + c];
    xm2 = (float)xz[(mb + ts - 2) * (long)NXZ + c];
    xm1 = (float)xz[(mb + ts - 1) * (long)NXZ + c];
  }

  for (int p = 0; p < 3; ++p) {
    const int tp = ts + p * 64;         // block-uniform
    __syncthreads();                    // protect previous panel before overwrite
    if (tp >= 0) {
#pragma unroll
      for (int j = 0; j < 8; ++j) {
        const int idx = j * 256 + tid, row = idx >> 5, col = (idx & 31) << 3;
        *(v8h*)&xs[row][col] = *(const v8h*)&xz[(mb + tp + row) * (long)NXZ + c0 + col];
      }
      if (p > 0) {
#pragma unroll
        for (int j = 0; j < 8; ++j) {
          const int idx = j * 256 + tid, row = idx >> 5, col = (idx & 31) << 3;
          *(v8h*)&zs[row][col] = *(const v8h*)&xz[(mb + tp + row) * (long)NXZ + D_INNER + c0 + col];
        }
      }
    }
    __syncthreads();
    if (tp < 0) continue;               // t<0: zero left-pad, h stays 0 (skip)
    if (p == 0) {
      // warm-up: EMA only, no output
      for (int tl = 0; tl < 64; ++tl) {
        float xt = (float)xs[tl][tid];
        float u = w0 * xm3 + w1 * xm2 + w2 * xm1 + w3 * xt + cb;
        h = 0.9f * h + 0.1f * (u / (1.f + __expf(-u)));
        xm3 = xm2; xm2 = xm1; xm1 = xt;
      }
    } else {
      f16* yo = y + (mb + tp) * (long)D_INNER + c;
      for (int tl = 0; tl < 64; ++tl) {
        float xt = (float)xs[tl][tid];
        float u = w0 * xm3 + w1 * xm2 + w2 * xm1 + w3 * xt + cb;
        float v = u / (1.f + __expf(-u));
        h = 0.9f * h + 0.1f * v;
        float zv = (float)zs[tl][tid];
        float g = zv / (1.f + __expf(-zv));
        yo[(long)tl * D_INNER] = (f16)((v * Dp + h) * g);
        xm3 = xm2; xm2 = xm1; xm1 = xt;
      }
    }
  }
}

// ---------------- launch ----------------
extern "C" void kernel_launch(void* const* d_in, const int* in_sizes, int n_in,
                              void* d_out, int out_size, void* d_ws, size_t ws_size,
                              hipStream_t stream) {
  const float* x       = (const float*)d_in[0];
  const float* in_w    = (const float*)d_in[1];
  const float* in_b    = (const float*)d_in[2];
  const float* conv_w  = (const float*)d_in[3];
  const float* conv_b  = (const float*)d_in[4];
  // d_in[5..8] (xp_w, xp_b, dt_w, dt_b) are dead code in the reference
  const float* D_param = (const float*)d_in[9];
  const float* out_w   = (const float*)d_in[10];
  const float* out_b   = (const float*)d_in[11];
  float* out = (float*)d_out;

  char* p = (char*)d_ws;
  f16* xb    = (f16*)p; p += (size_t)MTOT * D_MODEL * 2;   // 25.2 MB
  f16* wInT  = (f16*)p; p += (size_t)NXZ * D_MODEL * 2;    //  4.7 MB
  f16* wOutT = (f16*)p; p += (size_t)D_MODEL * D_INNER * 2;//  2.4 MB
  f16* xzb   = (f16*)p; p += (size_t)MTOT * NXZ * 2;       // 100.7 MB ([m][n])
  f16* yb    = (f16*)p; p += (size_t)MTOT * D_INNER * 2;   // 50.3 MB

  // prep
  k_cvt<<<(MTOT * D_MODEL / 4 + 255) / 256, 256, 0, stream>>>(x, xb, MTOT * D_MODEL / 4);
  k_transpose_cvt<<<dim3(NXZ / 32, D_MODEL / 32), dim3(32, 8), 0, stream>>>(in_w, wInT, D_MODEL, NXZ);
  k_transpose_cvt<<<dim3(D_MODEL / 32, D_INNER / 32), dim3(32, 8), 0, stream>>>(out_w, wOutT, D_INNER, D_MODEL);

  // xz = x @ in_w + in_b   (f16, [m][n])
  k_gemm_bt<true><<<dim3(NXZ / 128, MTOT / 128), 256, 0, stream>>>(xb, wInT, in_b, xzb, MTOT, NXZ, D_MODEL);

  // conv + silu + EMA scan + gate -> y (f16, [m][c])
  k_conv_scan<<<dim3(SEQ / 128, D_INNER / 256, BATCH), 256, 0, stream>>>(xzb, conv_w, conv_b, D_param, yb);

  // out = y @ out_w + out_b  (f32, [m][n])
  k_gemm_bt<false><<<dim3(D_MODEL / 128, MTOT / 128), 256, 0, stream>>>(yb, wOutT, out_b, out, MTOT, D_MODEL, D_INNER);
}